// Round 9
// baseline (336.088 us; speedup 1.0000x reference)
//
#include <hip/hip_runtime.h>
#include <hip/hip_bf16.h>
#include <stdint.h>

namespace {

constexpr int B = 8, T = 200, U = 50, D = 512, INNER = 640, VOCAB = 1024;
constexpr int M_TOTAL = B * T * U;          // 80000
constexpr int ROWS_E = B * T;               // 1600
constexpr int ROWS_D = B * U;               // 400
constexpr int ROWS_ED = ROWS_E + ROWS_D;    // 2000

typedef __bf16 bf16x8 __attribute__((ext_vector_type(8)));
typedef float  f32x4  __attribute__((ext_vector_type(4)));
typedef int    i32x4  __attribute__((ext_vector_type(4)));
typedef unsigned short u16;
typedef unsigned int   u32;

constexpr size_t ED_BYTES  = (size_t)ROWS_ED * INNER * 4;      // 5,120,000
constexpr size_t W2B_BYTES = (size_t)VOCAB * INNER * 2;        // 1,310,720
constexpr size_t H_BYTES   = (size_t)M_TOTAL * INNER * 2;      // 102,400,000
constexpr size_t WS_NEED   = ED_BYTES + W2B_BYTES + H_BYTES;   // 108,830,720

__device__ __forceinline__ u16 f2bf(float f) {
  uint32_t u = __float_as_uint(f);
  uint32_t rounding = 0x7FFFu + ((u >> 16) & 1u);   // RNE
  return (u16)((u + rounding) >> 16);
}

__device__ __forceinline__ float fast_tanh(float x) {
  float e = __expf(2.0f * x);
  float r = __builtin_amdgcn_rcpf(e + 1.0f);
  return 1.0f - 2.0f * r;
}

// ---------------------------------------------------------------------------
// k_prep: merged GEMM1 (ED) + W2 fragment pack (proven R5-R7).
//   blocks [0,500):   ED, 4 rows/block
//   blocks [500,756): W2B bf16 fragment pack
// Fragment f = ks*64+nf (1 KiB); lane l: {n = nf*16+(l&15), k = ks*32+(l>>4)*8+j}
// ---------------------------------------------------------------------------
__global__ __launch_bounds__(320) void k_prep(const float* __restrict__ enc,
                                              const float* __restrict__ dec,
                                              const float* __restrict__ W1,
                                              const float* __restrict__ b1,
                                              const float* __restrict__ W2,
                                              float* __restrict__ ED,
                                              u16* __restrict__ W2B) {
  if (blockIdx.x >= 500) {
    const int idx = (blockIdx.x - 500) * 320 + threadIdx.x;   // < 81920 exact
    const int lane = idx & 63;
    const int f = idx >> 6;
    const int ks = f >> 6;
    const int nf = f & 63;
    const int n = nf * 16 + (lane & 15);
    const int k = ks * 32 + (lane >> 4) * 8;
    u16 v[8];
#pragma unroll
    for (int j = 0; j < 8; ++j)
      v[j] = f2bf(W2[(size_t)(k + j) * VOCAB + n]);
    uint64_t lo = (uint64_t)v[0] | ((uint64_t)v[1] << 16) |
                  ((uint64_t)v[2] << 32) | ((uint64_t)v[3] << 48);
    uint64_t hi = (uint64_t)v[4] | ((uint64_t)v[5] << 16) |
                  ((uint64_t)v[6] << 32) | ((uint64_t)v[7] << 48);
    uint64_t* dst = reinterpret_cast<uint64_t*>(W2B + (size_t)idx * 8);
    dst[0] = lo;
    dst[1] = hi;
    return;
  }

  __shared__ float rows[4 * D];   // 8 KiB
  const int r0 = blockIdx.x * 4;
  const bool is_enc = (r0 < ROWS_E);
  const float* src = is_enc ? (enc + (size_t)r0 * D)
                            : (dec + (size_t)(r0 - ROWS_E) * D);
  for (int i = threadIdx.x; i < 4 * D; i += 320) rows[i] = src[i];
  __syncthreads();

  const int c0 = threadIdx.x, c1 = threadIdx.x + 320;
  float acc[4][2];
  const float bias0 = is_enc ? b1[c0] : 0.f;
  const float bias1 = is_enc ? b1[c1] : 0.f;
#pragma unroll
  for (int r = 0; r < 4; ++r) { acc[r][0] = bias0; acc[r][1] = bias1; }

  for (int d = 0; d < D; d += 8) {
    f32x4 rv[4][2];
#pragma unroll
    for (int r = 0; r < 4; ++r) {
      rv[r][0] = *reinterpret_cast<const f32x4*>(&rows[r * D + d]);
      rv[r][1] = *reinterpret_cast<const f32x4*>(&rows[r * D + d + 4]);
    }
#pragma unroll
    for (int dd = 0; dd < 8; ++dd) {
      const float w0 = W1[(size_t)(d + dd) * INNER + c0];
      const float w1 = W1[(size_t)(d + dd) * INNER + c1];
#pragma unroll
      for (int r = 0; r < 4; ++r) {
        const float x = rv[r][dd >> 2][dd & 3];
        acc[r][0] = fmaf(x, w0, acc[r][0]);
        acc[r][1] = fmaf(x, w1, acc[r][1]);
      }
    }
  }
#pragma unroll
  for (int r = 0; r < 4; ++r) {
    ED[(size_t)(r0 + r) * INNER + c0] = acc[r][0];
    ED[(size_t)(r0 + r) * INNER + c1] = acc[r][1];
  }
}

// ---------------------------------------------------------------------------
// k_h: H = tanh(E1 + D1), written in MFMA A-fragment order.
// Frag (mg, ksg): 16 rows x 32 k, 1 KiB; lane l holds 8 bf16
//   {m = mg*16 + (l&15), k = ksg*32 + (l>>4)*8 + j}.
// 1250 blocks x 256 thr; wave handles one mg (4 waves/block, mg < 5000).
// ---------------------------------------------------------------------------
__global__ __launch_bounds__(256) void k_h(const float* __restrict__ ED,
                                           u16* __restrict__ H) {
  const int lane = threadIdx.x & 63;
  const int mg = blockIdx.x * 4 + (threadIdx.x >> 6);   // 0..4999
  const int m = mg * 16 + (lane & 15);
  const int b = m / (T * U);
  const int rem = m - b * (T * U);
  const int t = rem / U;
  const int u = rem - t * U;
  const float* E  = ED + (size_t)(b * T + t) * INNER + (lane >> 4) * 8;
  const float* Dv = ED + (size_t)(ROWS_E + b * U + u) * INNER + (lane >> 4) * 8;
  u16* W = H + (size_t)mg * 20 * 512 + lane * 8;

#pragma unroll 4
  for (int ksg = 0; ksg < 20; ++ksg) {
    const f32x4 e0 = *reinterpret_cast<const f32x4*>(E + ksg * 32);
    const f32x4 e1 = *reinterpret_cast<const f32x4*>(E + ksg * 32 + 4);
    const f32x4 d0 = *reinterpret_cast<const f32x4*>(Dv + ksg * 32);
    const f32x4 d1 = *reinterpret_cast<const f32x4*>(Dv + ksg * 32 + 4);
    i32x4 pk;
    pk.x = (int)((u32)f2bf(fast_tanh(e0[0] + d0[0])) |
                 ((u32)f2bf(fast_tanh(e0[1] + d0[1])) << 16));
    pk.y = (int)((u32)f2bf(fast_tanh(e0[2] + d0[2])) |
                 ((u32)f2bf(fast_tanh(e0[3] + d0[3])) << 16));
    pk.z = (int)((u32)f2bf(fast_tanh(e1[0] + d1[0])) |
                 ((u32)f2bf(fast_tanh(e1[1] + d1[1])) << 16));
    pk.w = (int)((u32)f2bf(fast_tanh(e1[2] + d1[2])) |
                 ((u32)f2bf(fast_tanh(e1[3] + d1[3])) << 16));
    __builtin_nontemporal_store(pk, reinterpret_cast<i32x4*>(W + (size_t)ksg * 512));
  }
}

// ---------------------------------------------------------------------------
// k_main: pure GEMM out = H @ W2 + b2. Both operands fragment-packed ->
// ZERO LDS, ZERO barriers. 2500 blocks x 512 thr (8 waves, 2x4 of 64x64).
// launch_bounds(512,4): 2 blocks/CU = 16 independent waves, pure TLP.
// Bijective XCD-chunk swizzle: 4 same-mt siblings adjacent -> L2 shares H-tile.
// ---------------------------------------------------------------------------
__global__ __launch_bounds__(512, 4) void k_main(const u16* __restrict__ H,
                                                 const u16* __restrict__ W2B,
                                                 const float* __restrict__ b2,
                                                 float* __restrict__ out) {
  // bijective XCD chunk map (m204): NWG=2500, q=312, r=4
  const int bid = blockIdx.x;
  const int xcd = bid & 7;
  const int idx = bid >> 3;
  const int wg = (xcd < 4) ? xcd * 313 + idx : 4 * 313 + (xcd - 4) * 312 + idx;
  const int n0 = (wg & 3) * 256;
  const int mt = wg >> 2;          // 0..624

  const int tid  = threadIdx.x;
  const int lane = tid & 63;
  const int wid  = tid >> 6;
  const int wr = wid >> 2, wc = wid & 3;
  const int llo = lane & 15, lhi = lane >> 4;

  // A frag (mg, ks) at H + (mg*20 + ks)*512 ; wave's mg = mt*8 + wr*4 + mi
  const u16* Ap = H + ((size_t)(mt * 8 + wr * 4) * 20) * 512 + lane * 8;
  // B frag (ks, nf) at W2B + (ks*64 + nf)*512 ; wave's nf = n0/16 + wc*4 + ni
  const u16* Bq = W2B + ((size_t)((n0 >> 4) + wc * 4)) * 512 + lane * 8;

  f32x4 acc[4][4];
#pragma unroll
  for (int mi = 0; mi < 4; ++mi)
#pragma unroll
    for (int ni = 0; ni < 4; ++ni) acc[mi][ni] = (f32x4){0.f, 0.f, 0.f, 0.f};

  bf16x8 a[4];
#pragma unroll
  for (int mi = 0; mi < 4; ++mi)
    a[mi] = *reinterpret_cast<const bf16x8*>(Ap + (size_t)mi * 10240);

#pragma unroll
  for (int ks = 0; ks < 20; ++ks) {
    bf16x8 bfr[4];
#pragma unroll
    for (int ni = 0; ni < 4; ++ni)
      bfr[ni] = *reinterpret_cast<const bf16x8*>(
          Bq + (size_t)ks * 32768 + ni * 512);
    bf16x8 an[4];
    if (ks < 19) {
#pragma unroll
      for (int mi = 0; mi < 4; ++mi)
        an[mi] = *reinterpret_cast<const bf16x8*>(
            Ap + (size_t)mi * 10240 + (ks + 1) * 512);
    }
#pragma unroll
    for (int mi = 0; mi < 4; ++mi)
#pragma unroll
      for (int ni = 0; ni < 4; ++ni)
        acc[mi][ni] = __builtin_amdgcn_mfma_f32_16x16x32_bf16(a[mi], bfr[ni], acc[mi][ni], 0, 0, 0);
    if (ks < 19) {
#pragma unroll
      for (int mi = 0; mi < 4; ++mi) a[mi] = an[mi];
    }
  }

  float b2v[4];
#pragma unroll
  for (int ni = 0; ni < 4; ++ni) b2v[ni] = b2[n0 + wc * 64 + ni * 16 + llo];

#pragma unroll
  for (int mi = 0; mi < 4; ++mi) {
#pragma unroll
    for (int q = 0; q < 4; ++q) {
      const int row = mt * 128 + wr * 64 + mi * 16 + lhi * 4 + q;
      float* orow = out + (size_t)row * VOCAB + n0 + wc * 64 + llo;
#pragma unroll
      for (int ni = 0; ni < 4; ++ni)
        __builtin_nontemporal_store(acc[mi][ni][q] + b2v[ni], orow + ni * 16);
    }
  }
}

// ---------------------------------------------------------------------------
// FALLBACK (ws too small for H): R7's fused k_main — proven 178.6 µs path.
// ---------------------------------------------------------------------------
__global__ __launch_bounds__(512, 4) void k_main_fused(const float* __restrict__ ED,
                                                       const u16* __restrict__ W2B,
                                                       const float* __restrict__ b2,
                                                       float* __restrict__ out) {
  constexpr int CK = 128, NCHUNK = 5, CHUNK_B = 16 * 1024;
  __shared__ u16 At[2 * CHUNK_B / 2];
  char* At_b = reinterpret_cast<char*>(At);

  const int tid = threadIdx.x;
  const int m0 = blockIdx.x * 64;
  const int n0 = blockIdx.y * 512;

  const int row0 = tid >> 4;
  const int g    = tid & 15;
  int eoff[2], doff[2], wbyte[2];
#pragma unroll
  for (int i = 0; i < 2; ++i) {
    const int row = row0 + i * 32;
    const int m = m0 + row;
    const int b = m / (T * U);
    const int rem = m - b * (T * U);
    const int t = rem / U;
    const int u = rem - t * U;
    eoff[i] = (b * T + t) * INNER;
    doff[i] = (ROWS_E + b * U + u) * INNER;
    wbyte[i] = (((row >> 4) * 4 + (g >> 2)) << 10) + ((g & 3) * 16 + (row & 15)) * 16;
  }

  auto tanh_chunk = [&](int c, int bufsel) __attribute__((always_inline)) {
    const int kb = c * CK + g * 8;
#pragma unroll
    for (int i = 0; i < 2; ++i) {
      const float* E = ED + eoff[i] + kb;
      const float* Dp = ED + doff[i] + kb;
      const f32x4 e0 = *reinterpret_cast<const f32x4*>(E);
      const f32x4 e1 = *reinterpret_cast<const f32x4*>(E + 4);
      const f32x4 d0 = *reinterpret_cast<const f32x4*>(Dp);
      const f32x4 d1 = *reinterpret_cast<const f32x4*>(Dp + 4);
      const u32 p0 = (u32)f2bf(fast_tanh(e0[0] + d0[0])) |
                     ((u32)f2bf(fast_tanh(e0[1] + d0[1])) << 16);
      const u32 p1 = (u32)f2bf(fast_tanh(e0[2] + d0[2])) |
                     ((u32)f2bf(fast_tanh(e0[3] + d0[3])) << 16);
      const u32 p2 = (u32)f2bf(fast_tanh(e1[0] + d1[0])) |
                     ((u32)f2bf(fast_tanh(e1[1] + d1[1])) << 16);
      const u32 p3 = (u32)f2bf(fast_tanh(e1[2] + d1[2])) |
                     ((u32)f2bf(fast_tanh(e1[3] + d1[3])) << 16);
      int4 pk; pk.x = (int)p0; pk.y = (int)p1; pk.z = (int)p2; pk.w = (int)p3;
      *reinterpret_cast<int4*>(At_b + bufsel * CHUNK_B + wbyte[i]) = pk;
    }
  };

  const int lane = tid & 63;
  const int w    = tid >> 6;
  const int llo  = lane & 15;
  const int lhi  = lane >> 4;
  const u16* Bp = W2B + ((size_t)((n0 >> 4) + w * 4) << 9) + lane * 8;

  f32x4 acc[4][4];
#pragma unroll
  for (int mi = 0; mi < 4; ++mi)
#pragma unroll
    for (int ni = 0; ni < 4; ++ni) acc[mi][ni] = (f32x4){0.f, 0.f, 0.f, 0.f};

  tanh_chunk(0, 0);
  __syncthreads();

  for (int c = 0; c < NCHUNK; ++c) {
    const int ab = (c & 1) * CHUNK_B;
    if (c < NCHUNK - 1) tanh_chunk(c + 1, (c + 1) & 1);
#pragma unroll
    for (int ks = 0; ks < 4; ++ks) {
      bf16x8 bfr[4], a[4];
#pragma unroll
      for (int ni = 0; ni < 4; ++ni)
        bfr[ni] = *reinterpret_cast<const bf16x8*>(
            Bp + ((size_t)((c * 4 + ks) * 64 + ni) << 9));
#pragma unroll
      for (int mi = 0; mi < 4; ++mi)
        a[mi] = *reinterpret_cast<const bf16x8*>(
            At_b + ab + ((mi * 4 + ks) << 10) + lane * 16);
#pragma unroll
      for (int mi = 0; mi < 4; ++mi)
#pragma unroll
        for (int ni = 0; ni < 4; ++ni)
          acc[mi][ni] = __builtin_amdgcn_mfma_f32_16x16x32_bf16(a[mi], bfr[ni], acc[mi][ni], 0, 0, 0);
    }
    __syncthreads();
  }

  float b2v[4];
#pragma unroll
  for (int ni = 0; ni < 4; ++ni) b2v[ni] = b2[n0 + w * 64 + ni * 16 + llo];
#pragma unroll
  for (int mi = 0; mi < 4; ++mi) {
#pragma unroll
    for (int q = 0; q < 4; ++q) {
      const int row = m0 + mi * 16 + lhi * 4 + q;
      float* orow = out + (size_t)row * VOCAB + n0 + w * 64 + llo;
#pragma unroll
      for (int ni = 0; ni < 4; ++ni)
        __builtin_nontemporal_store(acc[mi][ni][q] + b2v[ni], orow + ni * 16);
    }
  }
}

}  // namespace

extern "C" void kernel_launch(void* const* d_in, const int* in_sizes, int n_in,
                              void* d_out, int out_size, void* d_ws, size_t ws_size,
                              hipStream_t stream) {
  const float* enc = (const float*)d_in[0];
  const float* dec = (const float*)d_in[1];
  const float* W1  = (const float*)d_in[2];
  const float* b1  = (const float*)d_in[3];
  const float* W2  = (const float*)d_in[4];
  const float* b2  = (const float*)d_in[5];
  float* out = (float*)d_out;

  float* ED  = (float*)d_ws;
  u16*   W2B = (u16*)((char*)d_ws + ED_BYTES);
  u16*   H   = (u16*)((char*)d_ws + ED_BYTES + W2B_BYTES);

  hipLaunchKernelGGL(k_prep, dim3(756), dim3(320), 0, stream,
                     enc, dec, W1, b1, W2, ED, W2B);

  if (ws_size >= WS_NEED) {
    hipLaunchKernelGGL(k_h, dim3(1250), dim3(256), 0, stream, ED, H);
    hipLaunchKernelGGL(k_main, dim3(2500), dim3(512), 0, stream,
                       H, W2B, b2, out);
  } else {
    hipLaunchKernelGGL(k_main_fused, dim3(M_TOTAL / 64, VOCAB / 512), dim3(512),
                       0, stream, ED, W2B, b2, out);
  }
}